// Round 13
// baseline (277.014 us; speedup 1.0000x reference)
//
#include <hip/hip_runtime.h>
#include <hip/hip_bf16.h>

#define NTOKENS 500000
#define NSAMPLED 8192
#define NHID 256
#define BATCH 8192
#define LROW 8193  // 1 + NSAMPLED
#define OUT_TAIL ((size_t)BATCH * LROW)

typedef short s16x8 __attribute__((ext_vector_type(8)));
typedef float f32x4 __attribute__((ext_vector_type(4)));
typedef unsigned short u16;

// RNE float->bf16
static __device__ __forceinline__ u16 f2bf(float f) {
  unsigned u = __float_as_uint(f);
  return (u16)((u + 0x7fffu + ((u >> 16) & 1u)) >> 16);
}

static __device__ __forceinline__ s16x8 pack8(float4 v0, float4 v1) {
  s16x8 o;
  o[0] = (short)f2bf(v0.x); o[1] = (short)f2bf(v0.y);
  o[2] = (short)f2bf(v0.z); o[3] = (short)f2bf(v0.w);
  o[4] = (short)f2bf(v1.x); o[5] = (short)f2bf(v1.y);
  o[6] = (short)f2bf(v1.z); o[7] = (short)f2bf(v1.w);
  return o;
}

static __device__ __forceinline__ void gload_lds16(const void* g, void* l) {
  __builtin_amdgcn_global_load_lds(
      (const __attribute__((address_space(1))) void*)g,
      (__attribute__((address_space(3))) void*)l, 16, 0, 0);
}

// ---- fused prep: [0,1024) A->bf16 | [1024,2048) gather B->bf16 + colconst
//                  | [2048,4096) true logits + zero targets ----
__global__ void k_prep(const float* __restrict__ inputs, const int* __restrict__ labels,
                       const int* __restrict__ sample_ids, const float* __restrict__ tfreq,
                       const float* __restrict__ sfreq, const float* __restrict__ weight,
                       const float* __restrict__ bias, u16* __restrict__ outA,
                       u16* __restrict__ outB, float* __restrict__ colconst,
                       float* __restrict__ out) {
  int bid = blockIdx.x;
  int t = threadIdx.x;
  if (bid < 1024) {                       // inputs fp32 -> bf16 [BATCH][NHID]
    size_t idx = ((size_t)bid * 256 + t) * 8;
    const float4* p = (const float4*)(inputs + idx);
    *(s16x8*)(outA + idx) = pack8(p[0], p[1]);
  } else if (bid < 2048) {                // gather weight[sample_ids] -> bf16; colconst
    int r = (bid - 1024) * 8 + (t >> 5);
    int l = t & 31;
    int s = sample_ids[r];
    const float* src = weight + (size_t)s * NHID + l * 8;
    *(s16x8*)(outB + (size_t)r * NHID + l * 8) =
        pack8(((const float4*)src)[0], ((const float4*)src)[1]);
    if (l == 0) colconst[r] = bias[s] - sfreq[r];
  } else {                                // true logits (col 0) + int32 zeros tail
    int bb = bid - 2048;
    int w = t >> 6, lane = t & 63;
    int b = bb * 4 + w;
    int lab = labels[b];
    const float4 x = *(const float4*)(inputs + (size_t)b * NHID + lane * 4);
    const float4 ww = *(const float4*)(weight + (size_t)lab * NHID + lane * 4);
    float s = x.x * ww.x + x.y * ww.y + x.z * ww.z + x.w * ww.w;
    #pragma unroll
    for (int off = 32; off; off >>= 1) s += __shfl_down(s, off, 64);
    if (lane == 0) out[(size_t)b * LROW] = s + bias[lab] - tfreq[b];
    int tid = bb * 256 + t;
    if (tid < BATCH) out[OUT_TAIL + tid] = 0.0f;
  }
}

// ---- GEMM (DIAGNOSTIC ROUND): r10 kernel + DOUBLE-STORE epilogue ----
// Purpose: decompose the ~75us GEMM. Output is written TWICE (identical
// values, same addresses; pass 1 volatile, passes barrier-separated so both
// reach the memory system; per-XCD inter-pass write volume > L2 so pass 2
// largely re-misses to HBM). Correctness unchanged; write traffic ~2x.
// Read: delta >= +25us => write-path-bound (r5/r10 near roofline);
//       delta <= +12us => writes have slack => compute/LDS side is the 75us.
__global__ __launch_bounds__(512, 4) void k_gemm(const u16* __restrict__ A,
                                                 const u16* __restrict__ B,
                                                 const float* __restrict__ colconst,
                                                 float* __restrict__ out) {
  __shared__ u16 lA[128 * 64];  // [row 0..127][k 0..63], XOR-swizzled chunks
  __shared__ u16 lB[256 * 64];  // [col 0..255][k 0..63]
  int t = threadIdx.x;
  int lane = t & 63;
  int w = t >> 6;               // 0..7
  int bid = blockIdx.x;
  int brow = bid >> 5;          // 0..63 (128-row tiles), row-major mapping
  int bcol = bid & 31;          // 0..31 (256-col tiles)
  int wr = w >> 1, wc = w & 1;  // wave: rows wr*32+, cols wc*128+
  const int l15 = lane & 15;
  const int lhi = lane >> 4;

  f32x4 acc[2][8];
  #pragma unroll
  for (int a = 0; a < 2; ++a)
    #pragma unroll
    for (int b = 0; b < 8; ++b) acc[a][b] = (f32x4){0.f, 0.f, 0.f, 0.f};

  const u16* Abase = A + (size_t)brow * 128 * NHID;
  const u16* Bbase = B + (size_t)bcol * 256 * NHID;

  for (int kt = 0; kt < 4; ++kt) {
    #pragma unroll
    for (int j = 0; j < 2; ++j) {
      int chunk = w * 128 + j * 64 + lane;
      int row = chunk >> 3;
      int cs = (chunk & 7) ^ (row & 7);
      gload_lds16(Abase + (size_t)row * NHID + kt * 64 + cs * 8,
                  lA + (size_t)(w * 128 + j * 64) * 8);
    }
    #pragma unroll
    for (int j = 0; j < 4; ++j) {
      int chunk = w * 256 + j * 64 + lane;
      int row = chunk >> 3;
      int cs = (chunk & 7) ^ (row & 7);
      gload_lds16(Bbase + (size_t)row * NHID + kt * 64 + cs * 8,
                  lB + (size_t)(w * 256 + j * 64) * 8);
    }
    __syncthreads();
    #pragma unroll
    for (int ks = 0; ks < 2; ++ks) {
      int kc = ks * 4 + lhi;
      s16x8 af[2];
      #pragma unroll
      for (int mi = 0; mi < 2; ++mi) {
        int row = wr * 32 + mi * 16 + l15;
        af[mi] = *(const s16x8*)(lA + row * 64 + ((kc ^ (row & 7)) * 8));
      }
      #pragma unroll
      for (int ni = 0; ni < 8; ++ni) {
        int row = wc * 128 + ni * 16 + l15;
        s16x8 bf = *(const s16x8*)(lB + row * 64 + ((kc ^ (row & 7)) * 8));
        #pragma unroll
        for (int mi = 0; mi < 2; ++mi)
          acc[mi][ni] = __builtin_amdgcn_mfma_f32_16x16x32_bf16(af[mi], bf, acc[mi][ni], 0, 0, 0);
      }
    }
    __syncthreads();
  }

  int grow0 = brow * 128 + wr * 32;
  int gcol0 = bcol * 256 + wc * 128;
  float cc[8];
  #pragma unroll
  for (int ni = 0; ni < 8; ++ni) cc[ni] = colconst[gcol0 + ni * 16 + l15];

  // PASS 1: volatile stores (must reach memory, cannot be elided)
  volatile float* vout = out;
  #pragma unroll
  for (int mi = 0; mi < 2; ++mi) {
    #pragma unroll
    for (int r = 0; r < 4; ++r) {
      size_t rbase = (size_t)(grow0 + mi * 16 + lhi * 4 + r) * LROW + 1;
      #pragma unroll
      for (int ni = 0; ni < 8; ++ni)
        vout[rbase + gcol0 + ni * 16 + l15] = acc[mi][ni][r] + cc[ni];
    }
  }
  __syncthreads();                 // separate the passes in time
  asm volatile("" ::: "memory");   // no cross-pass store merging
  // PASS 2: plain stores, same values/addresses (idempotent; extra traffic)
  #pragma unroll
  for (int mi = 0; mi < 2; ++mi) {
    #pragma unroll
    for (int r = 0; r < 4; ++r) {
      size_t rbase = (size_t)(grow0 + mi * 16 + lhi * 4 + r) * LROW + 1;
      #pragma unroll
      for (int ni = 0; ni < 8; ++ni)
        out[rbase + gcol0 + ni * 16 + l15] = acc[mi][ni][r] + cc[ni];
    }
  }
}

extern "C" void kernel_launch(void* const* d_in, const int* in_sizes, int n_in,
                              void* d_out, int out_size, void* d_ws, size_t ws_size,
                              hipStream_t stream) {
  const float* inputs          = (const float*)d_in[0];
  const int*   labels          = (const int*)d_in[1];
  const int*   sample_ids      = (const int*)d_in[2];
  const float* true_log_freq   = (const float*)d_in[3];
  const float* sample_log_freq = (const float*)d_in[4];
  const float* weight          = (const float*)d_in[5];
  const float* bias            = (const float*)d_in[6];
  float* out = (float*)d_out;

  u16* wsA = (u16*)d_ws;                                      // 4 MB
  u16* wsB = wsA + (size_t)BATCH * NHID;                      // 4 MB
  float* colconst = (float*)(wsB + (size_t)NSAMPLED * NHID);  // 32 KB

  hipLaunchKernelGGL(k_prep, dim3(4096), dim3(256), 0, stream,
                     inputs, labels, sample_ids, true_log_freq, sample_log_freq,
                     weight, bias, wsA, wsB, colconst, out);
  hipLaunchKernelGGL(k_gemm, dim3(2048), dim3(512), 0, stream, wsA, wsB, colconst, out);
}